// Round 12
// baseline (134.340 us; speedup 1.0000x reference)
//
#include <hip/hip_runtime.h>
#include <hip/hip_bf16.h>
#include <math.h>

#define B_   4
#define C_   128
#define H_   48
#define W_   48
#define HW_  2304
#define CG_  64
#define DH_  32
#define NZ_  4
#define SCALE_ 0.17677669529663687f   // 32^-0.5
#define QS_    (0.17677669529663687f * 1.4426950408889634f)  // SCALE * log2(e)
#define INVQ_  (1.0f / QS_)

// d_out layout (floats)
#define Y_OFF   0
#define POS_OFF 1179648
#define REF_OFF 1216512

// workspace layout (float offsets)
#define OFF_XTBF  0         // ushort[4][2304][128]  x^T bf16
#define OFF_QBF   589824    // ushort[4][2304][128]  q*QS bf16 [m][c]
#define OFF_KBF   1179648   // ushort[4][2304][128]  k bf16 [n][c]
#define OFF_VBF   1769472   // ushort[4][128][2304]  v bf16 [c][n] (k-slot permuted per 32-n group)
#define OFF_XST   2359296   // ushort[4][2304][128]  xs bf16 [p][c]
#define OFF_WBF   2949120   // ushort[4][16384]      qW,kW,vW,oW bf16
#define OFF_PRS   2981888   // float[4][16][2304]    partial rowsums
#define OFF_PROH  4161536   // _Float16[4][4*2304*128] partial O fp16
#define OFF_SMAPD 7184384   // double[8][2304]
#define OFF_WEFF  7221248   // double[258]

typedef __attribute__((ext_vector_type(8))) short short8;
typedef __attribute__((ext_vector_type(4))) float f32x4;
typedef __attribute__((ext_vector_type(8))) _Float16 f16x8;

__device__ inline unsigned short f2bf(float f) {
  unsigned u = __float_as_uint(f);
  u += 0x7fff + ((u >> 16) & 1);     // RNE
  return (unsigned short)(u >> 16);
}
__device__ inline float bf2f(unsigned short s) {
  return __uint_as_float(((unsigned)s) << 16);
}

// pack 8 f32 -> short8 of bf16 via v_cvt_pk_bf16_f32 (RNE), 4 ops
__device__ inline short8 pack8(const f32x4 a, const f32x4 b) {
  union { unsigned u[4]; short8 s; } r;
  asm("v_cvt_pk_bf16_f32 %0, %1, %2" : "=v"(r.u[0]) : "v"(a[0]), "v"(a[1]));
  asm("v_cvt_pk_bf16_f32 %0, %1, %2" : "=v"(r.u[1]) : "v"(a[2]), "v"(a[3]));
  asm("v_cvt_pk_bf16_f32 %0, %1, %2" : "=v"(r.u[2]) : "v"(b[0]), "v"(b[1]));
  asm("v_cvt_pk_bf16_f32 %0, %1, %2" : "=v"(r.u[3]) : "v"(b[2]), "v"(b[3]));
  return r.s;
}

// ---------------- fused: transpose x -> xTbf (blocks 0..287), weights->bf16 (288..543), weff (544) ----------------
__global__ __launch_bounds__(256) void k_pre(const float* __restrict__ x,
                                             const float* __restrict__ qW, const float* __restrict__ kW,
                                             const float* __restrict__ vW, const float* __restrict__ oW,
                                             const float* __restrict__ qb,
                                             const float* __restrict__ sob_w, const float* __restrict__ sob_b,
                                             unsigned short* __restrict__ xTbf,
                                             unsigned short* __restrict__ wbf,
                                             double* __restrict__ weff) {
  int bx = blockIdx.x;
  if (bx < 288) {
    __shared__ float tile[64][65];
    int p0 = (bx % 36) * 64, c0 = ((bx / 36) & 1) * 64, b = bx / 72;
    for (int idx = threadIdx.x; idx < 4096; idx += 256) {
      int cr = idx >> 6, pc = idx & 63;
      tile[cr][pc] = x[((size_t)(b * C_) + c0 + cr) * HW_ + p0 + pc];
    }
    __syncthreads();
    for (int idx = threadIdx.x; idx < 4096; idx += 256) {
      int pr = idx >> 6, cc = idx & 63;
      xTbf[((size_t)(b * HW_) + p0 + pr) * C_ + c0 + cc] = f2bf(tile[cc][pr]);
    }
  } else if (bx < 544) {
    int t = (bx - 288) * 256 + threadIdx.x;   // 65536
    int which = t >> 14, i = t & 16383;
    const float* src = which == 0 ? qW : which == 1 ? kW : which == 2 ? vW : oW;
    wbf[t] = f2bf(src[i]);
  } else {
    int t = threadIdx.x;
    int g = t >> 7, i = t & 127;
    double acc = 0.0;
    for (int c = 0; c < 64; c++)
      acc += (double)sob_w[c] * (double)qW[(size_t)(g * 64 + c) * C_ + i];
    weff[t] = acc;
    if (t < 2) {
      double bb = (double)sob_b[0];
      for (int c = 0; c < 64; c++) bb += (double)sob_w[c] * (double)qb[t * 64 + c];
      weff[256 + t] = bb;
    }
  }
}

// ---------------- fused: q-conv MFMA (blocks 0..575) + fp64 sobel s-map (576..647) ----------------
__global__ __launch_bounds__(256, 4) void k_qconv_smapd(const unsigned short* __restrict__ xTbf,
                                                        const unsigned short* __restrict__ wbf,
                                                        const float* __restrict__ qb,
                                                        const float* __restrict__ x,
                                                        const double* __restrict__ weff,
                                                        unsigned short* __restrict__ qbf,
                                                        double* __restrict__ smapd) {
  int bx = blockIdx.x;
  if (bx < 576) {
    int t = threadIdx.x, w = t >> 6, l = t & 63, lg = l >> 4, lo = l & 15;
    int m0 = (bx % 144) * 16, b = bx / 144, o0 = w * 32;
    const unsigned short* xrow = xTbf + ((size_t)(b * HW_) + m0 + lo) * C_ + lg * 8;
    f32x4 acc[2] = {{0.f,0.f,0.f,0.f},{0.f,0.f,0.f,0.f}};
#pragma unroll
    for (int kb = 0; kb < 4; kb++) {
      short8 xf = *(const short8*)(xrow + kb * 32);
#pragma unroll
      for (int os = 0; os < 2; os++) {
        short8 wf = *(const short8*)(wbf + (size_t)(o0 + os * 16 + lo) * C_ + kb * 32 + lg * 8);
        acc[os] = __builtin_amdgcn_mfma_f32_16x16x32_bf16(xf, wf, acc[os], 0, 0, 0);
      }
    }
#pragma unroll
    for (int os = 0; os < 2; os++) {
      int o = o0 + os * 16 + lo;
      float bi = qb[o];
#pragma unroll
      for (int r = 0; r < 4; r++) {
        int m = m0 + lg * 4 + r;
        qbf[((size_t)(b * HW_) + m) * C_ + o] = f2bf((acc[os][r] + bi) * QS_);
      }
    }
  } else {
    int bb = bx - 576;
    int p = (bb % 9) * 256 + threadIdx.x;
    int bg = bb / 9;
    int b = bg >> 1, g = bg & 1;
    const float* xb = x + (size_t)b * C_ * HW_ + p;
    const double* wv = weff + g * 128;
    double acc = weff[256 + g];
#pragma unroll 8
    for (int i = 0; i < 128; i++) acc += wv[i] * (double)xb[(size_t)i * HW_];
    smapd[bg * HW_ + p] = acc;
  }
}

// ---------------- fused offset branch + sobel gate + pos/ref + bilinear sample ----------------
__global__ __launch_bounds__(256) void k_offpos_sample(const unsigned short* __restrict__ qbf,
                                                       const double* __restrict__ s_map,
                                                       const float* __restrict__ dw_w,
                                                       const float* __restrict__ dw_b,
                                                       const float* __restrict__ ln_g,
                                                       const float* __restrict__ ln_b,
                                                       const float* __restrict__ pw_w,
                                                       const unsigned short* __restrict__ xTbf,
                                                       float* __restrict__ out,
                                                       unsigned short* __restrict__ xsT) {
  int widx = blockIdx.x * 4 + (threadIdx.x >> 6);
  int lane = threadIdx.x & 63;
  int bg = widx / HW_;
  int p = widx - bg * HW_;
  int h = p / W_, w = p - h * W_;
  int b = bg >> 1, g = bg & 1;
  const unsigned short* qc = qbf + (size_t)(b * HW_) * C_ + g * 64 + lane;
  float tv = dw_b[lane];
#pragma unroll
  for (int dy = -1; dy <= 1; dy++)
#pragma unroll
    for (int dx = -1; dx <= 1; dx++) {
      int hh = h + dy, ww = w + dx;
      if (hh >= 0 && hh < H_ && ww >= 0 && ww < W_) {
        float wgt = dw_w[lane * 9 + (dy + 1) * 3 + (dx + 1)] * INVQ_;
        tv += wgt * bf2f(qc[(size_t)(hh * W_ + ww) * C_]);
      }
    }
  float ssum = tv, ssq = tv * tv;
#pragma unroll
  for (int msk = 32; msk; msk >>= 1) {
    ssum += __shfl_xor(ssum, msk, 64);
    ssq  += __shfl_xor(ssq,  msk, 64);
  }
  float mu  = ssum * (1.0f / 64.0f);
  float var = ssq * (1.0f / 64.0f) - mu * mu;
  float uu  = (tv - mu) * rsqrtf(var + 1e-5f) * ln_g[lane] + ln_b[lane];
  float gl = 0.5f * uu * (1.0f + erff(uu * 0.70710678118654752f));
  float p0 = pw_w[lane] * gl, p1 = pw_w[64 + lane] * gl;
#pragma unroll
  for (int msk = 32; msk; msk >>= 1) {
    p0 += __shfl_xor(p0, msk, 64);
    p1 += __shfl_xor(p1, msk, 64);
  }
  const double sobx[9] = {-1., 0., 1., -2., 0., 2., -1., 0., 1.};
  const double soby[9] = {-1., -2., -1., 0., 0., 0., 1., 2., 1.};
  float off_y = tanhf(p0) * (1.0f / 47.0f);
  float off_x = tanhf(p1) * (1.0f / 47.0f);
  const double* sm = s_map + bg * HW_;
  double gx = 0., gy = 0.;
#pragma unroll
  for (int dy = -1; dy <= 1; dy++)
#pragma unroll
    for (int dx = -1; dx <= 1; dx++) {
      int hh = h + dy, ww = w + dx;
      if (hh >= 0 && hh < H_ && ww >= 0 && ww < W_) {
        double sv = sm[hh * W_ + ww];
        gx += sobx[(dy + 1) * 3 + dx + 1] * sv;
        gy += soby[(dy + 1) * 3 + dx + 1] * sv;
      }
    }
  double mag = sqrt(gx * gx + gy * gy);
  float bin = mag > 0.5 ? 1.0f : 0.0f;
  float ry = ((h + 0.5f) / 47.0f) * 2.0f - 1.0f;
  float rx = ((w + 0.5f) / 47.0f) * 2.0f - 1.0f;
  float py = off_y + ry * bin;
  float px = off_x + rx * bin;
  if (lane == 0) {
    int pi = (bg * HW_ + p) * 2;
    out[POS_OFF + pi]     = py;
    out[POS_OFF + pi + 1] = px;
    out[REF_OFF + pi]     = ry;
    out[REF_OFF + pi + 1] = rx;
  }
  float gxf = (px + 1.0f) * 0.5f * 47.0f;
  float gyf = (py + 1.0f) * 0.5f * 47.0f;
  float x0 = floorf(gxf), y0 = floorf(gyf);
  float wx1 = gxf - x0, wy1 = gyf - y0;
  float wx0 = 1.0f - wx1, wy0 = 1.0f - wy1;
  const unsigned short* base = xTbf + (size_t)(b * HW_) * C_ + g * 64 + lane;
  float acc = 0.0f;
#pragma unroll
  for (int cy = 0; cy < 2; cy++)
#pragma unroll
    for (int cx = 0; cx < 2; cx++) {
      float yy = y0 + (float)cy, xx = x0 + (float)cx;
      bool valid = (yy >= 0.f) && (yy < 48.f) && (xx >= 0.f) && (xx < 48.f);
      int yc = min(max((int)yy, 0), 47);
      int xc = min(max((int)xx, 0), 47);
      float wgt = (cy ? wy1 : wy0) * (cx ? wx1 : wx0);
      float vv = valid ? bf2f(base[(size_t)(yc * 48 + xc) * C_]) : 0.0f;
      acc += wgt * vv;
    }
  xsT[((size_t)(b * HW_) + p) * C_ + g * 64 + lane] = f2bf(acc);
}

// ---------------- k/v conv (MFMA): kbf[n][c]; vbf[c][n] written k-slot-permuted ----------------
__global__ __launch_bounds__(256, 4) void k_kvconv(const unsigned short* __restrict__ xsT,
                                                   const unsigned short* __restrict__ wbf,
                                                   const float* __restrict__ kbias,
                                                   const float* __restrict__ vbias,
                                                   unsigned short* __restrict__ kbf,
                                                   unsigned short* __restrict__ vbf) {
  int t = threadIdx.x, w = t >> 6, l = t & 63, lg = l >> 4, lo = l & 15;
  int n0 = blockIdx.x * 16, b = blockIdx.y, o0 = w * 32;
  const unsigned short* xrow = xsT + ((size_t)(b * HW_) + n0 + lo) * C_ + lg * 8;
  const unsigned short* wk = wbf + 16384;
  const unsigned short* wv = wbf + 32768;
  f32x4 ak[2] = {{0.f,0.f,0.f,0.f},{0.f,0.f,0.f,0.f}};
  f32x4 av[2] = {{0.f,0.f,0.f,0.f},{0.f,0.f,0.f,0.f}};
#pragma unroll
  for (int kb = 0; kb < 4; kb++) {
    short8 xf = *(const short8*)(xrow + kb * 32);
#pragma unroll
    for (int os = 0; os < 2; os++) {
      size_t wo = (size_t)(o0 + os * 16 + lo) * C_ + kb * 32 + lg * 8;
      short8 wkf = *(const short8*)(wk + wo);
      short8 wvf = *(const short8*)(wv + wo);
      ak[os] = __builtin_amdgcn_mfma_f32_16x16x32_bf16(xf, wkf, ak[os], 0, 0, 0);
      av[os] = __builtin_amdgcn_mfma_f32_16x16x32_bf16(wvf, xf, av[os], 0, 0, 0);
    }
  }
  int o32 = (n0 & 16) + lo;
  int vpos = (n0 & ~31) + ((o32 & 12) << 1) + (o32 & 3) + ((o32 >> 4) << 2);
#pragma unroll
  for (int os = 0; os < 2; os++) {
    int ok = o0 + os * 16 + lo;
    float bk_ = kbias[ok];
#pragma unroll
    for (int r = 0; r < 4; r++) {
      int n = n0 + lg * 4 + r;
      kbf[((size_t)(b * HW_) + n) * C_ + ok] = f2bf(ak[os][r] + bk_);
      int ov = o0 + os * 16 + lg * 4 + r;
      vbf[((size_t)(b * C_) + ov) * HW_ + vpos] = f2bf(av[os][r] + vbias[ov]);
    }
  }
}

// ---------------- MFMA flash attention v9: 32 m-rows/wave, 2-wave blocks ----------------
#define EXPROW(SV, RS)                                                              \
  _Pragma("unroll")                                                                 \
  for (int r = 0; r < 4; r++) {                                                     \
    float e0, e1, e2, e3;                                                           \
    asm("v_exp_f32 %0, %1" : "=v"(e0) : "v"(SV##0[r]));                             \
    asm("v_exp_f32 %0, %1" : "=v"(e1) : "v"(SV##1[r]));                             \
    asm("v_exp_f32 %0, %1" : "=v"(e2) : "v"(SV##2[r]));                             \
    asm("v_exp_f32 %0, %1" : "=v"(e3) : "v"(SV##3[r]));                             \
    SV##0[r] = e0; SV##1[r] = e1; SV##2[r] = e2; SV##3[r] = e3;                     \
    RS += (e0 + e1) + (e2 + e3);                                                    \
  }

#define ATTN_BODY5(BK, BKN, DOPREF)                                                 \
  {                                                                                 \
    short8 bv0 = *(const short8*)(vr0 + n0);                                        \
    short8 bv1 = *(const short8*)(vr0 + n0 + 32);                                   \
    short8 bv2 = *(const short8*)(vr1 + n0);                                        \
    short8 bv3 = *(const short8*)(vr1 + n0 + 32);                                   \
    if (DOPREF) {                                                                   \
      _Pragma("unroll")                                                             \
      for (int sub = 0; sub < 4; sub++)                                             \
        BKN[sub] = *(const short8*)(kb_ + (size_t)(n0 + 64 + sub * 16 + lo) * C_);  \
    }                                                                               \
    f32x4 z = {0.f, 0.f, 0.f, 0.f};                                                 \
    __builtin_amdgcn_s_setprio(1);                                                  \
    f32x4 s0 = __builtin_amdgcn_mfma_f32_16x16x32_bf16(BK[0], aq0, z, 0, 0, 0);     \
    f32x4 s1 = __builtin_amdgcn_mfma_f32_16x16x32_bf16(BK[1], aq0, z, 0, 0, 0);     \
    f32x4 s2 = __builtin_amdgcn_mfma_f32_16x16x32_bf16(BK[2], aq0, z, 0, 0, 0);     \
    f32x4 s3 = __builtin_amdgcn_mfma_f32_16x16x32_bf16(BK[3], aq0, z, 0, 0, 0);     \
    __builtin_amdgcn_s_setprio(0);                                                  \
    EXPROW(s, rsum0)                                                                \
    short8 pa0 = pack8(s0, s1), pa1 = pack8(s2, s3);                                \
    __builtin_amdgcn_s_setprio(1);                                                  \
    f32x4 t0 = __builtin_amdgcn_mfma_f32_16x16x32_bf16(BK[0], aq1, z, 0, 0, 0);     \
    f32x4 t1 = __builtin_amdgcn_mfma_f32_16x16x32_bf16(BK[1], aq1, z, 0, 0, 0);     \
    f32x4 t2 = __builtin_amdgcn_mfma_f32_16x16x32_bf16(BK[2], aq1, z, 0, 0, 0);     \
    f32x4 t3 = __builtin_amdgcn_mfma_f32_16x16x32_bf16(BK[3], aq1, z, 0, 0, 0);     \
    acc00 = __builtin_amdgcn_mfma_f32_16x16x32_bf16(pa0, bv0, acc00, 0, 0, 0);      \
    acc00 = __builtin_amdgcn_mfma_f32_16x16x32_bf16(pa1, bv1, acc00, 0, 0, 0);      \
    acc01 = __builtin_amdgcn_mfma_f32_16x16x32_bf16(pa0, bv2, acc01, 0, 0, 0);      \
    acc01 = __builtin_amdgcn_mfma_f32_16x16x32_bf16(pa1, bv3, acc01, 0, 0, 0);      \
    __builtin_amdgcn_s_setprio(0);                                                  \
    EXPROW(t, rsum1)                                                                \
    short8 pb0 = pack8(t0, t1), pb1 = pack8(t2, t3);                                \
    __builtin_amdgcn_s_setprio(1);                                                  \
    acc10 = __builtin_amdgcn_mfma_f32_16x16x32_bf16(pb0, bv0, acc10, 0, 0, 0);      \
    acc10 = __builtin_amdgcn_mfma_f32_16x16x32_bf16(pb1, bv1, acc10, 0, 0, 0);      \
    acc11 = __builtin_amdgcn_mfma_f32_16x16x32_bf16(pb0, bv2, acc11, 0, 0, 0);      \
    acc11 = __builtin_amdgcn_mfma_f32_16x16x32_bf16(pb1, bv3, acc11, 0, 0, 0);      \
    __builtin_amdgcn_s_setprio(0);                                                  \
    n0 += 64;                                                                       \
  }

__global__ __launch_bounds__(128) void k_attn9(const unsigned short* __restrict__ qbf,
                                               const unsigned short* __restrict__ kbf,
                                               const unsigned short* __restrict__ vpf,
                                               _Float16* __restrict__ prOh,
                                               float* __restrict__ prS) {
  int t = threadIdx.x, w = t >> 6, l = t & 63, lg = l >> 4, lo = l & 15;
  int bh = blockIdx.y, b = bh >> 2, hd = bh & 3, nz = blockIdx.z;
  int cb = hd * 32;
  int m0 = blockIdx.x * 64 + w * 32;
  const unsigned short* qrow = qbf + ((size_t)(b * HW_) + m0 + lo) * C_ + cb + lg * 8;
  short8 aq0 = *(const short8*)qrow;
  short8 aq1 = *(const short8*)(qrow + (size_t)16 * C_);
  const unsigned short* kb_ = kbf + (size_t)(b * HW_) * C_ + cb + lg * 8;
  const unsigned short* vr0 = vpf + (size_t)(b * C_ + cb + lo) * HW_ + lg * 8;
  const unsigned short* vr1 = vr0 + (size_t)16 * HW_;
  f32x4 acc00 = {0.f,0.f,0.f,0.f}, acc01 = {0.f,0.f,0.f,0.f};
  f32x4 acc10 = {0.f,0.f,0.f,0.f}, acc11 = {0.f,0.f,0.f,0.f};
  float rsum0 = 0.f, rsum1 = 0.f;
  int n0 = nz * 576;
  short8 bkA[4], bkB[4];
#pragma unroll
  for (int sub = 0; sub < 4; sub++)
    bkA[sub] = *(const short8*)(kb_ + (size_t)(n0 + sub * 16 + lo) * C_);
  for (int i4 = 0; i4 < 4; i4++) {
    ATTN_BODY5(bkA, bkB, true)
    ATTN_BODY5(bkB, bkA, (i4 < 3))
  }
  ATTN_BODY5(bkA, bkB, false)
  rsum0 += __shfl_xor(rsum0, 16, 64);
  rsum0 += __shfl_xor(rsum0, 32, 64);
  rsum1 += __shfl_xor(rsum1, 16, 64);
  rsum1 += __shfl_xor(rsum1, 32, 64);
  _Float16* pr = prOh + (size_t)nz * (B_ * HW_ * C_);
#pragma unroll
  for (int r = 0; r < 4; r++) {
    int m = m0 + lg * 4 + r;
    size_t oi = ((size_t)(b * HW_) + m) * C_ + cb;
    pr[oi + lo] = (_Float16)acc00[r];
    pr[oi + 16 + lo] = (_Float16)acc01[r];
    size_t oi2 = oi + (size_t)16 * C_;
    pr[oi2 + lo] = (_Float16)acc10[r];
    pr[oi2 + 16 + lo] = (_Float16)acc11[r];
  }
  if (l < 16) {
    prS[((size_t)(nz * 16) + bh) * HW_ + m0 + lo] = rsum0;
    prS[((size_t)(nz * 16) + bh) * HW_ + m0 + 16 + lo] = rsum1;
  }
}

// ---------------- fused combine + LEPE + o-conv: y = oW·(ΣO/Σr + lepe) + ob ----------------
__global__ __launch_bounds__(256) void k_out(const _Float16* __restrict__ prOh,
                                             const float* __restrict__ prS,
                                             const unsigned short* __restrict__ qbf,
                                             const float* __restrict__ rpe_w,
                                             const float* __restrict__ rpe_b,
                                             const unsigned short* __restrict__ wbf,
                                             const float* __restrict__ ob_,
                                             float* __restrict__ y) {
  __shared__ __align__(16) unsigned short lds[16][136];
  int t = threadIdx.x;
  int m0 = blockIdx.x * 16, b = blockIdx.y;
  {
    int mi = t >> 4, c8 = (t & 15) * 8;
    int m = m0 + mi;
    int hd = c8 >> 5;
    size_t oi = ((size_t)(b * HW_) + m) * C_ + c8;
    float rs = 0.f;
    float o[8] = {0.f,0.f,0.f,0.f,0.f,0.f,0.f,0.f};
#pragma unroll
    for (int nz = 0; nz < NZ_; nz++) {
      rs += prS[((size_t)(nz * 16) + b * 4 + hd) * HW_ + m];
      f16x8 v = *(const f16x8*)(prOh + (size_t)nz * (B_ * HW_ * C_) + oi);
#pragma unroll
      for (int j = 0; j < 8; j++) o[j] += (float)v[j];
    }
    float inv = 1.0f / rs;
    int h = m / W_, ww0 = m - h * W_;
    float lp[8];
#pragma unroll
    for (int j = 0; j < 8; j++) lp[j] = rpe_b[c8 + j];
#pragma unroll
    for (int dy = -1; dy <= 1; dy++)
#pragma unroll
      for (int dx = -1; dx <= 1; dx++) {
        int hh = h + dy, ww = ww0 + dx;
        if (hh >= 0 && hh < H_ && ww >= 0 && ww < W_) {
          int idx = (dy + 1) * 3 + (dx + 1);
          short8 q8 = *(const short8*)(qbf + ((size_t)(b * HW_) + hh * W_ + ww) * C_ + c8);
#pragma unroll
          for (int j = 0; j < 8; j++)
            lp[j] += rpe_w[(c8 + j) * 9 + idx] * INVQ_ * bf2f((unsigned short)q8[j]);
        }
      }
    short8 res;
#pragma unroll
    for (int j = 0; j < 8; j++) res[j] = (short)f2bf(o[j] * inv + lp[j]);
    *(short8*)&lds[mi][c8] = res;
  }
  __syncthreads();
  int w = t >> 6, l = t & 63, lg = l >> 4, lo = l & 15;
  int o0 = w * 32;
  const unsigned short* wo = wbf + 49152;
  f32x4 acc[2] = {{0.f,0.f,0.f,0.f},{0.f,0.f,0.f,0.f}};
#pragma unroll
  for (int kb = 0; kb < 4; kb++) {
    short8 xf = *(const short8*)&lds[lo][kb * 32 + lg * 8];
#pragma unroll
    for (int os = 0; os < 2; os++) {
      short8 wf = *(const short8*)(wo + (size_t)(o0 + os * 16 + lo) * C_ + kb * 32 + lg * 8);
      acc[os] = __builtin_amdgcn_mfma_f32_16x16x32_bf16(wf, xf, acc[os], 0, 0, 0);
    }
  }
#pragma unroll
  for (int os = 0; os < 2; os++)
#pragma unroll
    for (int r = 0; r < 4; r++) {
      int o = o0 + os * 16 + lg * 4 + r;
      y[((size_t)(b * C_) + o) * HW_ + m0 + lo] = acc[os][r] + ob_[o];
    }
}

extern "C" void kernel_launch(void* const* d_in, const int* in_sizes, int n_in,
                              void* d_out, int out_size, void* d_ws, size_t ws_size,
                              hipStream_t stream) {
  const float* x        = (const float*)d_in[0];
  const float* qW       = (const float*)d_in[1];
  const float* qb       = (const float*)d_in[2];
  const float* kW       = (const float*)d_in[3];
  const float* kb       = (const float*)d_in[4];
  const float* vW       = (const float*)d_in[5];
  const float* vb       = (const float*)d_in[6];
  const float* oW       = (const float*)d_in[7];
  const float* ob       = (const float*)d_in[8];
  const float* off_dw_w = (const float*)d_in[9];
  const float* off_dw_b = (const float*)d_in[10];
  const float* ln_g     = (const float*)d_in[11];
  const float* ln_b     = (const float*)d_in[12];
  const float* off_pw_w = (const float*)d_in[13];
  const float* sob_w    = (const float*)d_in[14];
  const float* sob_b    = (const float*)d_in[15];
  const float* rpe_w    = (const float*)d_in[16];
  const float* rpe_b    = (const float*)d_in[17];
  float* out = (float*)d_out;
  float* wsf = (float*)d_ws;
  unsigned short* xTbf  = (unsigned short*)(wsf + OFF_XTBF);
  unsigned short* qbf   = (unsigned short*)(wsf + OFF_QBF);
  unsigned short* kbf   = (unsigned short*)(wsf + OFF_KBF);
  unsigned short* vbf   = (unsigned short*)(wsf + OFF_VBF);
  unsigned short* xsT   = (unsigned short*)(wsf + OFF_XST);
  unsigned short* wbf   = (unsigned short*)(wsf + OFF_WBF);
  float* prS   = wsf + OFF_PRS;
  _Float16* prOh = (_Float16*)(wsf + OFF_PROH);
  double* smapd = (double*)(wsf + OFF_SMAPD);
  double* weff  = (double*)(wsf + OFF_WEFF);

  k_pre          <<<545,             256, 0, stream>>>(x, qW, kW, vW, oW, qb, sob_w, sob_b,
                                                       xTbf, wbf, weff);
  k_qconv_smapd  <<<648,             256, 0, stream>>>(xTbf, wbf, qb, x, weff, qbf, smapd);
  k_offpos_sample<<<4608,            256, 0, stream>>>(qbf, smapd, off_dw_w, off_dw_b,
                                                       ln_g, ln_b, off_pw_w, xTbf, out, xsT);
  k_kvconv       <<<dim3(144, 4),    256, 0, stream>>>(xsT, wbf, kb, vb, kbf, vbf);
  k_attn9        <<<dim3(36, 16, 4), 128, 0, stream>>>(qbf, kbf, vbf, prOh, prS);
  k_out          <<<dim3(144, 4),    256, 0, stream>>>(prOh, prS, qbf, rpe_w, rpe_b,
                                                       wbf, ob, out + Y_OFF);
}

// Round 13
// 111.004 us; speedup vs baseline: 1.2102x; 1.2102x over previous
//
#include <hip/hip_runtime.h>
#include <hip/hip_bf16.h>
#include <math.h>

#define B_   4
#define C_   128
#define H_   48
#define W_   48
#define HW_  2304
#define CG_  64
#define DH_  32
#define NZ_  4
#define SCALE_ 0.17677669529663687f   // 32^-0.5
#define QS_    (0.17677669529663687f * 1.4426950408889634f)  // SCALE * log2(e)
#define INVQ_  (1.0f / QS_)

// d_out layout (floats)
#define Y_OFF   0
#define POS_OFF 1179648
#define REF_OFF 1216512

// workspace layout (float offsets)
#define OFF_XTBF  0         // ushort[4][2304][128]  x^T bf16
#define OFF_QBF   589824    // ushort[4][2304][128]  q*QS bf16 [m][c]
#define OFF_KBF   1179648   // ushort[4][2304][128]  k bf16 [n][c]
#define OFF_VBF   1769472   // ushort[4][128][2304]  v bf16 [c][n] (k-slot permuted per 32-n group)
#define OFF_XST   2359296   // ushort[4][2304][128]  xs bf16 [p][c]
#define OFF_WBF   2949120   // ushort[4][16384]      qW,kW,vW,oW bf16
#define OFF_PRS   2981888   // float[4][16][2304]    partial rowsums
#define OFF_PROH  4161536   // _Float16[4][4*2304*128] partial O fp16
#define OFF_SMAPD 7184384   // double[8][2304]
#define OFF_WEFF  7221248   // double[258]
#define OFF_AOUTT 7222000   // ushort[4][2304][128]  aout bf16 [m][c]

typedef __attribute__((ext_vector_type(8))) short short8;
typedef __attribute__((ext_vector_type(4))) float f32x4;
typedef __attribute__((ext_vector_type(4))) _Float16 f16x4;
typedef __attribute__((ext_vector_type(8))) _Float16 f16x8;

__device__ inline unsigned short f2bf(float f) {
  unsigned u = __float_as_uint(f);
  u += 0x7fff + ((u >> 16) & 1);     // RNE
  return (unsigned short)(u >> 16);
}
__device__ inline float bf2f(unsigned short s) {
  return __uint_as_float(((unsigned)s) << 16);
}

// pack 8 f32 -> short8 of bf16 via v_cvt_pk_bf16_f32 (RNE), 4 ops
__device__ inline short8 pack8(const f32x4 a, const f32x4 b) {
  union { unsigned u[4]; short8 s; } r;
  asm("v_cvt_pk_bf16_f32 %0, %1, %2" : "=v"(r.u[0]) : "v"(a[0]), "v"(a[1]));
  asm("v_cvt_pk_bf16_f32 %0, %1, %2" : "=v"(r.u[1]) : "v"(a[2]), "v"(a[3]));
  asm("v_cvt_pk_bf16_f32 %0, %1, %2" : "=v"(r.u[2]) : "v"(b[0]), "v"(b[1]));
  asm("v_cvt_pk_bf16_f32 %0, %1, %2" : "=v"(r.u[3]) : "v"(b[2]), "v"(b[3]));
  return r.s;
}

// ---------------- fused: transpose x -> xTbf (blocks 0..287), weights->bf16 (288..543), weff (544) ----------------
__global__ __launch_bounds__(256) void k_pre(const float* __restrict__ x,
                                             const float* __restrict__ qW, const float* __restrict__ kW,
                                             const float* __restrict__ vW, const float* __restrict__ oW,
                                             const float* __restrict__ qb,
                                             const float* __restrict__ sob_w, const float* __restrict__ sob_b,
                                             unsigned short* __restrict__ xTbf,
                                             unsigned short* __restrict__ wbf,
                                             double* __restrict__ weff) {
  int bx = blockIdx.x;
  if (bx < 288) {
    __shared__ float tile[64][65];
    int p0 = (bx % 36) * 64, c0 = ((bx / 36) & 1) * 64, b = bx / 72;
    for (int idx = threadIdx.x; idx < 4096; idx += 256) {
      int cr = idx >> 6, pc = idx & 63;
      tile[cr][pc] = x[((size_t)(b * C_) + c0 + cr) * HW_ + p0 + pc];
    }
    __syncthreads();
    for (int idx = threadIdx.x; idx < 4096; idx += 256) {
      int pr = idx >> 6, cc = idx & 63;
      xTbf[((size_t)(b * HW_) + p0 + pr) * C_ + c0 + cc] = f2bf(tile[cc][pr]);
    }
  } else if (bx < 544) {
    int t = (bx - 288) * 256 + threadIdx.x;   // 65536
    int which = t >> 14, i = t & 16383;
    const float* src = which == 0 ? qW : which == 1 ? kW : which == 2 ? vW : oW;
    wbf[t] = f2bf(src[i]);
  } else {
    int t = threadIdx.x;
    int g = t >> 7, i = t & 127;
    double acc = 0.0;
    for (int c = 0; c < 64; c++)
      acc += (double)sob_w[c] * (double)qW[(size_t)(g * 64 + c) * C_ + i];
    weff[t] = acc;
    if (t < 2) {
      double bb = (double)sob_b[0];
      for (int c = 0; c < 64; c++) bb += (double)sob_w[c] * (double)qb[t * 64 + c];
      weff[256 + t] = bb;
    }
  }
}

// ---------------- fused: q-conv MFMA (blocks 0..575) + fp64 sobel s-map (576..647) ----------------
__global__ __launch_bounds__(256, 4) void k_qconv_smapd(const unsigned short* __restrict__ xTbf,
                                                        const unsigned short* __restrict__ wbf,
                                                        const float* __restrict__ qb,
                                                        const float* __restrict__ x,
                                                        const double* __restrict__ weff,
                                                        unsigned short* __restrict__ qbf,
                                                        double* __restrict__ smapd) {
  int bx = blockIdx.x;
  if (bx < 576) {
    int t = threadIdx.x, w = t >> 6, l = t & 63, lg = l >> 4, lo = l & 15;
    int m0 = (bx % 144) * 16, b = bx / 144, o0 = w * 32;
    const unsigned short* xrow = xTbf + ((size_t)(b * HW_) + m0 + lo) * C_ + lg * 8;
    f32x4 acc[2] = {{0.f,0.f,0.f,0.f},{0.f,0.f,0.f,0.f}};
#pragma unroll
    for (int kb = 0; kb < 4; kb++) {
      short8 xf = *(const short8*)(xrow + kb * 32);
#pragma unroll
      for (int os = 0; os < 2; os++) {
        short8 wf = *(const short8*)(wbf + (size_t)(o0 + os * 16 + lo) * C_ + kb * 32 + lg * 8);
        acc[os] = __builtin_amdgcn_mfma_f32_16x16x32_bf16(xf, wf, acc[os], 0, 0, 0);
      }
    }
#pragma unroll
    for (int os = 0; os < 2; os++) {
      int o = o0 + os * 16 + lo;
      float bi = qb[o];
#pragma unroll
      for (int r = 0; r < 4; r++) {
        int m = m0 + lg * 4 + r;
        qbf[((size_t)(b * HW_) + m) * C_ + o] = f2bf((acc[os][r] + bi) * QS_);
      }
    }
  } else {
    int bb = bx - 576;
    int p = (bb % 9) * 256 + threadIdx.x;
    int bg = bb / 9;
    int b = bg >> 1, g = bg & 1;
    const float* xb = x + (size_t)b * C_ * HW_ + p;
    const double* wv = weff + g * 128;
    double acc = weff[256 + g];
#pragma unroll 8
    for (int i = 0; i < 128; i++) acc += wv[i] * (double)xb[(size_t)i * HW_];
    smapd[bg * HW_ + p] = acc;
  }
}

// ---------------- fused offset branch + sobel gate + pos/ref + bilinear sample ----------------
__global__ __launch_bounds__(256) void k_offpos_sample(const unsigned short* __restrict__ qbf,
                                                       const double* __restrict__ s_map,
                                                       const float* __restrict__ dw_w,
                                                       const float* __restrict__ dw_b,
                                                       const float* __restrict__ ln_g,
                                                       const float* __restrict__ ln_b,
                                                       const float* __restrict__ pw_w,
                                                       const unsigned short* __restrict__ xTbf,
                                                       float* __restrict__ out,
                                                       unsigned short* __restrict__ xsT) {
  int widx = blockIdx.x * 4 + (threadIdx.x >> 6);
  int lane = threadIdx.x & 63;
  int bg = widx / HW_;
  int p = widx - bg * HW_;
  int h = p / W_, w = p - h * W_;
  int b = bg >> 1, g = bg & 1;
  const unsigned short* qc = qbf + (size_t)(b * HW_) * C_ + g * 64 + lane;
  float tv = dw_b[lane];
#pragma unroll
  for (int dy = -1; dy <= 1; dy++)
#pragma unroll
    for (int dx = -1; dx <= 1; dx++) {
      int hh = h + dy, ww = w + dx;
      if (hh >= 0 && hh < H_ && ww >= 0 && ww < W_) {
        float wgt = dw_w[lane * 9 + (dy + 1) * 3 + (dx + 1)] * INVQ_;
        tv += wgt * bf2f(qc[(size_t)(hh * W_ + ww) * C_]);
      }
    }
  float ssum = tv, ssq = tv * tv;
#pragma unroll
  for (int msk = 32; msk; msk >>= 1) {
    ssum += __shfl_xor(ssum, msk, 64);
    ssq  += __shfl_xor(ssq,  msk, 64);
  }
  float mu  = ssum * (1.0f / 64.0f);
  float var = ssq * (1.0f / 64.0f) - mu * mu;
  float uu  = (tv - mu) * rsqrtf(var + 1e-5f) * ln_g[lane] + ln_b[lane];
  float gl = 0.5f * uu * (1.0f + erff(uu * 0.70710678118654752f));
  float p0 = pw_w[lane] * gl, p1 = pw_w[64 + lane] * gl;
#pragma unroll
  for (int msk = 32; msk; msk >>= 1) {
    p0 += __shfl_xor(p0, msk, 64);
    p1 += __shfl_xor(p1, msk, 64);
  }
  const double sobx[9] = {-1., 0., 1., -2., 0., 2., -1., 0., 1.};
  const double soby[9] = {-1., -2., -1., 0., 0., 0., 1., 2., 1.};
  float off_y = tanhf(p0) * (1.0f / 47.0f);
  float off_x = tanhf(p1) * (1.0f / 47.0f);
  const double* sm = s_map + bg * HW_;
  double gx = 0., gy = 0.;
#pragma unroll
  for (int dy = -1; dy <= 1; dy++)
#pragma unroll
    for (int dx = -1; dx <= 1; dx++) {
      int hh = h + dy, ww = w + dx;
      if (hh >= 0 && hh < H_ && ww >= 0 && ww < W_) {
        double sv = sm[hh * W_ + ww];
        gx += sobx[(dy + 1) * 3 + dx + 1] * sv;
        gy += soby[(dy + 1) * 3 + dx + 1] * sv;
      }
    }
  double mag = sqrt(gx * gx + gy * gy);
  float bin = mag > 0.5 ? 1.0f : 0.0f;
  float ry = ((h + 0.5f) / 47.0f) * 2.0f - 1.0f;
  float rx = ((w + 0.5f) / 47.0f) * 2.0f - 1.0f;
  float py = off_y + ry * bin;
  float px = off_x + rx * bin;
  if (lane == 0) {
    int pi = (bg * HW_ + p) * 2;
    out[POS_OFF + pi]     = py;
    out[POS_OFF + pi + 1] = px;
    out[REF_OFF + pi]     = ry;
    out[REF_OFF + pi + 1] = rx;
  }
  float gxf = (px + 1.0f) * 0.5f * 47.0f;
  float gyf = (py + 1.0f) * 0.5f * 47.0f;
  float x0 = floorf(gxf), y0 = floorf(gyf);
  float wx1 = gxf - x0, wy1 = gyf - y0;
  float wx0 = 1.0f - wx1, wy0 = 1.0f - wy1;
  const unsigned short* base = xTbf + (size_t)(b * HW_) * C_ + g * 64 + lane;
  float acc = 0.0f;
#pragma unroll
  for (int cy = 0; cy < 2; cy++)
#pragma unroll
    for (int cx = 0; cx < 2; cx++) {
      float yy = y0 + (float)cy, xx = x0 + (float)cx;
      bool valid = (yy >= 0.f) && (yy < 48.f) && (xx >= 0.f) && (xx < 48.f);
      int yc = min(max((int)yy, 0), 47);
      int xc = min(max((int)xx, 0), 47);
      float wgt = (cy ? wy1 : wy0) * (cx ? wx1 : wx0);
      float vv = valid ? bf2f(base[(size_t)(yc * 48 + xc) * C_]) : 0.0f;
      acc += wgt * vv;
    }
  xsT[((size_t)(b * HW_) + p) * C_ + g * 64 + lane] = f2bf(acc);
}

// ---------------- k/v conv (MFMA): kbf[n][c]; vbf[c][n] written k-slot-permuted ----------------
__global__ __launch_bounds__(256, 4) void k_kvconv(const unsigned short* __restrict__ xsT,
                                                   const unsigned short* __restrict__ wbf,
                                                   const float* __restrict__ kbias,
                                                   const float* __restrict__ vbias,
                                                   unsigned short* __restrict__ kbf,
                                                   unsigned short* __restrict__ vbf) {
  int t = threadIdx.x, w = t >> 6, l = t & 63, lg = l >> 4, lo = l & 15;
  int n0 = blockIdx.x * 16, b = blockIdx.y, o0 = w * 32;
  const unsigned short* xrow = xsT + ((size_t)(b * HW_) + n0 + lo) * C_ + lg * 8;
  const unsigned short* wk = wbf + 16384;
  const unsigned short* wv = wbf + 32768;
  f32x4 ak[2] = {{0.f,0.f,0.f,0.f},{0.f,0.f,0.f,0.f}};
  f32x4 av[2] = {{0.f,0.f,0.f,0.f},{0.f,0.f,0.f,0.f}};
#pragma unroll
  for (int kb = 0; kb < 4; kb++) {
    short8 xf = *(const short8*)(xrow + kb * 32);
#pragma unroll
    for (int os = 0; os < 2; os++) {
      size_t wo = (size_t)(o0 + os * 16 + lo) * C_ + kb * 32 + lg * 8;
      short8 wkf = *(const short8*)(wk + wo);
      short8 wvf = *(const short8*)(wv + wo);
      ak[os] = __builtin_amdgcn_mfma_f32_16x16x32_bf16(xf, wkf, ak[os], 0, 0, 0);
      av[os] = __builtin_amdgcn_mfma_f32_16x16x32_bf16(wvf, xf, av[os], 0, 0, 0);
    }
  }
  int o32 = (n0 & 16) + lo;
  int vpos = (n0 & ~31) + ((o32 & 12) << 1) + (o32 & 3) + ((o32 >> 4) << 2);
#pragma unroll
  for (int os = 0; os < 2; os++) {
    int ok = o0 + os * 16 + lo;
    float bk_ = kbias[ok];
#pragma unroll
    for (int r = 0; r < 4; r++) {
      int n = n0 + lg * 4 + r;
      kbf[((size_t)(b * HW_) + n) * C_ + ok] = f2bf(ak[os][r] + bk_);
      int ov = o0 + os * 16 + lg * 4 + r;
      vbf[((size_t)(b * C_) + ov) * HW_ + vpos] = f2bf(av[os][r] + vbias[ov]);
    }
  }
}

// ---------------- MFMA flash attention v6 (measured-best): 64 m-rows/wave, 4-stage stagger ----------------
#define EXPROW2(S0, S1, S2, S3, RS)                                                 \
  _Pragma("unroll")                                                                 \
  for (int r = 0; r < 4; r++) {                                                     \
    float e0, e1, e2, e3;                                                           \
    asm("v_exp_f32 %0, %1" : "=v"(e0) : "v"(S0[r]));                                \
    asm("v_exp_f32 %0, %1" : "=v"(e1) : "v"(S1[r]));                                \
    asm("v_exp_f32 %0, %1" : "=v"(e2) : "v"(S2[r]));                                \
    asm("v_exp_f32 %0, %1" : "=v"(e3) : "v"(S3[r]));                                \
    S0[r] = e0; S1[r] = e1; S2[r] = e2; S3[r] = e3;                                 \
    RS += (e0 + e1) + (e2 + e3);                                                    \
  }

#define QKT(BK, AQ, S0, S1, S2, S3)                                                 \
    S0 = __builtin_amdgcn_mfma_f32_16x16x32_bf16(BK[0], AQ, z, 0, 0, 0);            \
    S1 = __builtin_amdgcn_mfma_f32_16x16x32_bf16(BK[1], AQ, z, 0, 0, 0);            \
    S2 = __builtin_amdgcn_mfma_f32_16x16x32_bf16(BK[2], AQ, z, 0, 0, 0);            \
    S3 = __builtin_amdgcn_mfma_f32_16x16x32_bf16(BK[3], AQ, z, 0, 0, 0);

#define PVT(PA0, PA1, AL, AH)                                                       \
    AL = __builtin_amdgcn_mfma_f32_16x16x32_bf16(PA0, bv0, AL, 0, 0, 0);            \
    AL = __builtin_amdgcn_mfma_f32_16x16x32_bf16(PA1, bv1, AL, 0, 0, 0);            \
    AH = __builtin_amdgcn_mfma_f32_16x16x32_bf16(PA0, bv2, AH, 0, 0, 0);            \
    AH = __builtin_amdgcn_mfma_f32_16x16x32_bf16(PA1, bv3, AH, 0, 0, 0);

#define ATTN_BODY6(BK, BKN, DOPREF)                                                 \
  {                                                                                 \
    short8 bv0 = *(const short8*)(vr0 + n0);                                        \
    short8 bv1 = *(const short8*)(vr0 + n0 + 32);                                   \
    short8 bv2 = *(const short8*)(vr1 + n0);                                        \
    short8 bv3 = *(const short8*)(vr1 + n0 + 32);                                   \
    if (DOPREF) {                                                                   \
      _Pragma("unroll")                                                             \
      for (int sub = 0; sub < 4; sub++)                                             \
        BKN[sub] = *(const short8*)(kb_ + (size_t)(n0 + 64 + sub * 16 + lo) * C_);  \
    }                                                                               \
    f32x4 z = {0.f, 0.f, 0.f, 0.f};                                                 \
    f32x4 s0, s1, s2, s3, t0, t1, t2, t3;                                           \
    __builtin_amdgcn_s_setprio(1);                                                  \
    QKT(BK, aq0, s0, s1, s2, s3)                                                    \
    __builtin_amdgcn_s_setprio(0);                                                  \
    EXPROW2(s0, s1, s2, s3, rsv[0])                                                 \
    short8 pa0 = pack8(s0, s1), pa1 = pack8(s2, s3);                                \
    __builtin_amdgcn_s_setprio(1);                                                  \
    QKT(BK, aq1, t0, t1, t2, t3)                                                    \
    PVT(pa0, pa1, aL[0], aH[0])                                                     \
    __builtin_amdgcn_s_setprio(0);                                                  \
    EXPROW2(t0, t1, t2, t3, rsv[1])                                                 \
    short8 pb0 = pack8(t0, t1), pb1 = pack8(t2, t3);                                \
    __builtin_amdgcn_s_setprio(1);                                                  \
    QKT(BK, aq2, s0, s1, s2, s3)                                                    \
    PVT(pb0, pb1, aL[1], aH[1])                                                     \
    __builtin_amdgcn_s_setprio(0);                                                  \
    EXPROW2(s0, s1, s2, s3, rsv[2])                                                 \
    short8 pc0 = pack8(s0, s1), pc1 = pack8(s2, s3);                                \
    __builtin_amdgcn_s_setprio(1);                                                  \
    QKT(BK, aq3, t0, t1, t2, t3)                                                    \
    PVT(pc0, pc1, aL[2], aH[2])                                                     \
    __builtin_amdgcn_s_setprio(0);                                                  \
    EXPROW2(t0, t1, t2, t3, rsv[3])                                                 \
    short8 pd0 = pack8(t0, t1), pd1 = pack8(t2, t3);                                \
    __builtin_amdgcn_s_setprio(1);                                                  \
    PVT(pd0, pd1, aL[3], aH[3])                                                     \
    __builtin_amdgcn_s_setprio(0);                                                  \
    n0 += 64;                                                                       \
  }

__global__ __launch_bounds__(128, 2) void k_attn6(const unsigned short* __restrict__ qbf,
                                                  const unsigned short* __restrict__ kbf,
                                                  const unsigned short* __restrict__ vpf,
                                                  _Float16* __restrict__ prOh,
                                                  float* __restrict__ prS) {
  int t = threadIdx.x, w = t >> 6, l = t & 63, lg = l >> 4, lo = l & 15;
  int bh = blockIdx.y, b = bh >> 2, hd = bh & 3, nz = blockIdx.z;
  int cb = hd * 32;
  int m0 = blockIdx.x * 128 + w * 64;
  const unsigned short* qrow = qbf + ((size_t)(b * HW_) + m0 + lo) * C_ + cb + lg * 8;
  short8 aq0 = *(const short8*)qrow;
  short8 aq1 = *(const short8*)(qrow + (size_t)16 * C_);
  short8 aq2 = *(const short8*)(qrow + (size_t)32 * C_);
  short8 aq3 = *(const short8*)(qrow + (size_t)48 * C_);
  const unsigned short* kb_ = kbf + (size_t)(b * HW_) * C_ + cb + lg * 8;
  const unsigned short* vr0 = vpf + (size_t)(b * C_ + cb + lo) * HW_ + lg * 8;
  const unsigned short* vr1 = vr0 + (size_t)16 * HW_;
  f32x4 aL[4] = {{0.f,0.f,0.f,0.f},{0.f,0.f,0.f,0.f},{0.f,0.f,0.f,0.f},{0.f,0.f,0.f,0.f}};
  f32x4 aH[4] = {{0.f,0.f,0.f,0.f},{0.f,0.f,0.f,0.f},{0.f,0.f,0.f,0.f},{0.f,0.f,0.f,0.f}};
  f32x4 rsv = {0.f, 0.f, 0.f, 0.f};
  int n0 = nz * 576;
  short8 bkA[4], bkB[4];
#pragma unroll
  for (int sub = 0; sub < 4; sub++)
    bkA[sub] = *(const short8*)(kb_ + (size_t)(n0 + sub * 16 + lo) * C_);
  for (int i4 = 0; i4 < 4; i4++) {
    ATTN_BODY6(bkA, bkB, true)
    ATTN_BODY6(bkB, bkA, (i4 < 3))
  }
  ATTN_BODY6(bkA, bkB, false)
#pragma unroll
  for (int qi = 0; qi < 4; qi++) {
    rsv[qi] += __shfl_xor(rsv[qi], 16, 64);
    rsv[qi] += __shfl_xor(rsv[qi], 32, 64);
  }
  _Float16* pr = prOh + (size_t)nz * (B_ * HW_ * C_);
#pragma unroll
  for (int qi = 0; qi < 4; qi++) {
#pragma unroll
    for (int r = 0; r < 4; r++) {
      int m = m0 + qi * 16 + lg * 4 + r;
      size_t oi = ((size_t)(b * HW_) + m) * C_ + cb;
      pr[oi + lo] = (_Float16)aL[qi][r];
      pr[oi + 16 + lo] = (_Float16)aH[qi][r];
    }
  }
  if (l < 16) {
#pragma unroll
    for (int qi = 0; qi < 4; qi++)
      prS[((size_t)(nz * 16) + bh) * HW_ + m0 + qi * 16 + lo] = rsv[qi];
  }
}

// ---------------- combine + inline LEPE: aoutT[m][c] = bf16(ΣO/Σr + lepe) ----------------
__global__ __launch_bounds__(256) void k_combine2(const _Float16* __restrict__ prOh,
                                                  const float* __restrict__ prS,
                                                  const unsigned short* __restrict__ qbf,
                                                  const float* __restrict__ rpe_w,
                                                  const float* __restrict__ rpe_b,
                                                  unsigned short* __restrict__ aoutT) {
  size_t oi = ((size_t)blockIdx.x * 256 + threadIdx.x) * 4;
  int c = (int)(oi & 127);
  size_t bm = oi >> 7;                 // b*HW + m
  int b = (int)(bm / HW_);
  int m = (int)(bm - (size_t)b * HW_);
  int hd = c >> 5;
  int bh = b * 4 + hd;
  float rs = 0.f;
  float o[4] = {0.f, 0.f, 0.f, 0.f};
#pragma unroll
  for (int nz = 0; nz < NZ_; nz++) {
    rs += prS[((size_t)(nz * 16) + bh) * HW_ + m];
    f16x4 v = *(const f16x4*)(prOh + (size_t)nz * (B_ * HW_ * C_) + oi);
#pragma unroll
    for (int j = 0; j < 4; j++) o[j] += (float)v[j];
  }
  float inv = 1.0f / rs;
  int h = m / W_, w = m - (m / W_) * W_;
  float lp[4] = {rpe_b[c], rpe_b[c + 1], rpe_b[c + 2], rpe_b[c + 3]};
#pragma unroll
  for (int dy = -1; dy <= 1; dy++)
#pragma unroll
    for (int dx = -1; dx <= 1; dx++) {
      int hh = h + dy, ww = w + dx;
      if (hh >= 0 && hh < H_ && ww >= 0 && ww < W_) {
        int idx = (dy + 1) * 3 + (dx + 1);
        ushort4 q4 = *(const ushort4*)(qbf + ((size_t)(b * HW_) + hh * W_ + ww) * C_ + c);
        lp[0] += rpe_w[(c + 0) * 9 + idx] * INVQ_ * bf2f(q4.x);
        lp[1] += rpe_w[(c + 1) * 9 + idx] * INVQ_ * bf2f(q4.y);
        lp[2] += rpe_w[(c + 2) * 9 + idx] * INVQ_ * bf2f(q4.z);
        lp[3] += rpe_w[(c + 3) * 9 + idx] * INVQ_ * bf2f(q4.w);
      }
    }
  ushort4 pk;
  pk.x = f2bf(o[0] * inv + lp[0]);
  pk.y = f2bf(o[1] * inv + lp[1]);
  pk.z = f2bf(o[2] * inv + lp[2]);
  pk.w = f2bf(o[3] * inv + lp[3]);
  *(ushort4*)(aoutT + oi) = pk;
}

// ---------------- o-conv (MFMA): y[c][m] = oW·aoutT + ob ----------------
__global__ __launch_bounds__(256, 4) void k_oconv(const unsigned short* __restrict__ aoutT,
                                                  const unsigned short* __restrict__ wbf,
                                                  const float* __restrict__ ob_,
                                                  float* __restrict__ y) {
  int t = threadIdx.x, w = t >> 6, l = t & 63, lg = l >> 4, lo = l & 15;
  int m0 = blockIdx.x * 16, b = blockIdx.y, o0 = w * 32;
  const unsigned short* xrow = aoutT + ((size_t)(b * HW_) + m0 + lo) * C_ + lg * 8;
  const unsigned short* wo = wbf + 49152;
  f32x4 acc[2] = {{0.f,0.f,0.f,0.f},{0.f,0.f,0.f,0.f}};
#pragma unroll
  for (int kb = 0; kb < 4; kb++) {
    short8 xf = *(const short8*)(xrow + kb * 32);
#pragma unroll
    for (int os = 0; os < 2; os++) {
      short8 wf = *(const short8*)(wo + (size_t)(o0 + os * 16 + lo) * C_ + kb * 32 + lg * 8);
      acc[os] = __builtin_amdgcn_mfma_f32_16x16x32_bf16(wf, xf, acc[os], 0, 0, 0);
    }
  }
#pragma unroll
  for (int os = 0; os < 2; os++)
#pragma unroll
    for (int r = 0; r < 4; r++) {
      int o = o0 + os * 16 + lg * 4 + r;
      y[((size_t)(b * C_) + o) * HW_ + m0 + lo] = acc[os][r] + ob_[o];
    }
}

extern "C" void kernel_launch(void* const* d_in, const int* in_sizes, int n_in,
                              void* d_out, int out_size, void* d_ws, size_t ws_size,
                              hipStream_t stream) {
  const float* x        = (const float*)d_in[0];
  const float* qW       = (const float*)d_in[1];
  const float* qb       = (const float*)d_in[2];
  const float* kW       = (const float*)d_in[3];
  const float* kb       = (const float*)d_in[4];
  const float* vW       = (const float*)d_in[5];
  const float* vb       = (const float*)d_in[6];
  const float* oW       = (const float*)d_in[7];
  const float* ob       = (const float*)d_in[8];
  const float* off_dw_w = (const float*)d_in[9];
  const float* off_dw_b = (const float*)d_in[10];
  const float* ln_g     = (const float*)d_in[11];
  const float* ln_b     = (const float*)d_in[12];
  const float* off_pw_w = (const float*)d_in[13];
  const float* sob_w    = (const float*)d_in[14];
  const float* sob_b    = (const float*)d_in[15];
  const float* rpe_w    = (const float*)d_in[16];
  const float* rpe_b    = (const float*)d_in[17];
  float* out = (float*)d_out;
  float* wsf = (float*)d_ws;
  unsigned short* xTbf  = (unsigned short*)(wsf + OFF_XTBF);
  unsigned short* qbf   = (unsigned short*)(wsf + OFF_QBF);
  unsigned short* kbf   = (unsigned short*)(wsf + OFF_KBF);
  unsigned short* vbf   = (unsigned short*)(wsf + OFF_VBF);
  unsigned short* xsT   = (unsigned short*)(wsf + OFF_XST);
  unsigned short* wbf   = (unsigned short*)(wsf + OFF_WBF);
  unsigned short* aoutT = (unsigned short*)(wsf + OFF_AOUTT);
  float* prS   = wsf + OFF_PRS;
  _Float16* prOh = (_Float16*)(wsf + OFF_PROH);
  double* smapd = (double*)(wsf + OFF_SMAPD);
  double* weff  = (double*)(wsf + OFF_WEFF);

  k_pre          <<<545,             256, 0, stream>>>(x, qW, kW, vW, oW, qb, sob_w, sob_b,
                                                       xTbf, wbf, weff);
  k_qconv_smapd  <<<648,             256, 0, stream>>>(xTbf, wbf, qb, x, weff, qbf, smapd);
  k_offpos_sample<<<4608,            256, 0, stream>>>(qbf, smapd, off_dw_w, off_dw_b,
                                                       ln_g, ln_b, off_pw_w, xTbf, out, xsT);
  k_kvconv       <<<dim3(144, 4),    256, 0, stream>>>(xsT, wbf, kb, vb, kbf, vbf);
  k_attn6        <<<dim3(18, 16, 4), 128, 0, stream>>>(qbf, kbf, vbf, prOh, prS);
  k_combine2     <<<1152,            256, 0, stream>>>(prOh, prS, qbf, rpe_w, rpe_b, aoutT);
  k_oconv        <<<dim3(144, 4),    256, 0, stream>>>(aoutT, wbf, ob, out + Y_OFF);
}